// Round 9
// baseline (5247.305 us; speedup 1.0000x reference)
//
#include <hip/hip_runtime.h>
#include <stdint.h>

typedef unsigned long long u64;

#define NROW 12288
#define DFEAT 512
#define HDIM  1024

// ---------------- f32 NT GEMM, single ascending-k FMA chain per C element ----
// Hypothesis r9: BLIS/AOCL-style blocking — sgemm KC >= 512, so K=512 is ONE
// unsplit panel (k=0..511 sequential into a single accumulator) and K=1024
// splits as (512,512) merged with one f32 add. Panels p0..p3, 0-terminated.
// MODE 0: store relu(v + bias)      (h1, h2)
// MODE 1: store resid + (v + bias)  (feat = X + h)
// MODE 2: store relu(v)             (sim)
template <int MODE>
__global__ __launch_bounds__(256, 4) void gemmf(
    const float* __restrict__ A, const float* __restrict__ B,
    const float* __restrict__ bias, const float* __restrict__ resid,
    float* __restrict__ C, int Nn, int K,
    int p0, int p1, int p2, int p3)
{
  __shared__ float As[32][64];   // [k][m]
  __shared__ float Bs[32][64];   // [k][n]
  const int t = threadIdx.x;
  const int tm = t & 15, tn = t >> 4;
  const size_t m0 = (size_t)blockIdx.y * 64, n0 = (size_t)blockIdx.x * 64;

  float cur[4][4] = {};
  float tot[4][4];
  bool first = true;
  int pl[4] = {p0, p1, p2, p3};
  int pi = 0;
  int nb = pl[0];

  for (int kt = 0; kt < K; kt += 32) {
#pragma unroll
    for (int p = 0; p < 2; ++p) {
      int f = p * 256 + t;
      int r = f >> 3, c = f & 7;
      float4 va = *(const float4*)(A + (m0 + r) * (size_t)K + kt + 4 * c);
      As[4 * c + 0][r] = va.x; As[4 * c + 1][r] = va.y;
      As[4 * c + 2][r] = va.z; As[4 * c + 3][r] = va.w;
      float4 vb = *(const float4*)(B + (n0 + r) * (size_t)K + kt + 4 * c);
      Bs[4 * c + 0][r] = vb.x; Bs[4 * c + 1][r] = vb.y;
      Bs[4 * c + 2][r] = vb.z; Bs[4 * c + 3][r] = vb.w;
    }
    __syncthreads();
#pragma unroll
    for (int kk = 0; kk < 32; ++kk) {
      float4 a4 = *(const float4*)&As[kk][4 * tm];
      float4 b4 = *(const float4*)&Bs[kk][4 * tn];
      float av[4] = {a4.x, a4.y, a4.z, a4.w};
      float bv[4] = {b4.x, b4.y, b4.z, b4.w};
#pragma unroll
      for (int i = 0; i < 4; ++i)
#pragma unroll
        for (int j = 0; j < 4; ++j)
          cur[i][j] = fmaf(av[i], bv[j], cur[i][j]);   // k ascending, single acc
    }
    __syncthreads();
    int ke = kt + 32;
    if (ke == nb) {   // panel boundary: merge with ONE f32 add
      if (first) {
#pragma unroll
        for (int i = 0; i < 4; ++i)
#pragma unroll
          for (int j = 0; j < 4; ++j) { tot[i][j] = cur[i][j]; cur[i][j] = 0.f; }
        first = false;
      } else {
#pragma unroll
        for (int i = 0; i < 4; ++i)
#pragma unroll
          for (int j = 0; j < 4; ++j) { tot[i][j] = tot[i][j] + cur[i][j]; cur[i][j] = 0.f; }
      }
      if (++pi < 4 && pl[pi] > 0) nb = ke + pl[pi];
    }
  }

#pragma unroll
  for (int i = 0; i < 4; ++i) {
    size_t gm = m0 + 4 * tm + i;
    float4 res;
    float rv[4];
#pragma unroll
    for (int j = 0; j < 4; ++j) {
      size_t gn = n0 + 4 * tn + j;
      float v = tot[i][j];
      if (MODE == 0) {
        v = v + bias[gn];
        v = v > 0.f ? v : 0.f;
      } else if (MODE == 1) {
        v = v + bias[gn];
        v = resid[gm * (size_t)Nn + gn] + v;
      } else {
        v = v > 0.f ? v : 0.f;
      }
      rv[j] = v;
    }
    res.x = rv[0]; res.y = rv[1]; res.z = rv[2]; res.w = rv[3];
    *(float4*)(C + gm * (size_t)Nn + n0 + 4 * tn) = res;
  }
}

// ---------------- norm + fn: numpy classic pairwise base (8 scalar accumulators) ---
// s = x*x rounded separately; 512 -> 256+256 -> 128-blocks, each with 8 scalar
// accumulators (strided), combined ((r0+r1)+(r2+r3))+((r4+r5)+(r6+r7));
// S=(B0+B1)+(B2+B3). sqrt correctly rounded via f64, +1e-8f (no-op), IEEE divide.
__global__ __launch_bounds__(256) void norm_fn_kernel(const float* __restrict__ feat,
                                                      float* __restrict__ fn) {
#pragma clang fp contract(off)
  const int row = blockIdx.x * 4 + (threadIdx.x >> 6);
  const int lane = threadIdx.x & 63;
  const float* fr = feat + (size_t)row * DFEAT;
  float r = 0.f;
  if (lane < 32) {
    const float* bp = fr + (lane >> 3) * 128 + (lane & 7);
    float x = bp[0];
    r = x * x;
#pragma unroll
    for (int i = 8; i <= 120; i += 8) {
      float x2 = bp[i];
      float s = x2 * x2;
      r = r + s;
    }
  }
  float v[32];
#pragma unroll
  for (int j = 0; j < 32; ++j) v[j] = __shfl(r, j);
  float Bv[4];
#pragma unroll
  for (int b = 0; b < 4; ++b) {
    const float* p = v + 8 * b;
    Bv[b] = ((p[0] + p[1]) + (p[2] + p[3])) + ((p[4] + p[5]) + (p[6] + p[7]));
  }
  float S = (Bv[0] + Bv[1]) + (Bv[2] + Bv[3]);
  float den = (float)sqrt((double)S) + 1e-8f;
#pragma unroll
  for (int e = 0; e < 8; ++e) {
    int d = e * 64 + lane;
    fn[(size_t)row * DFEAT + d] = fr[d] / den;   // IEEE f32 divide
  }
}

// ---------------- per-row top-32 (lower-index tie-break) ----------------
#define TKT 192
__global__ __launch_bounds__(TKT) void topk_kernel(
    const float* __restrict__ sim, float* __restrict__ topv, int* __restrict__ topi)
{
  __shared__ u64 ck[32 * TKT];
  __shared__ u64 wbest[3];
  const int row = blockIdx.x, t = threadIdx.x;
  const float4* rp = (const float4*)(sim + (size_t)row * NROW);

  u64 mk = ~0ull; int ms = 0;
#pragma unroll
  for (int it = 0; it < 8; ++it) {
    float4 vq = rp[t + TKT * it];
    int jb = 4 * (t + TKT * it);
    float vv[4] = {vq.x, vq.y, vq.z, vq.w};
#pragma unroll
    for (int e = 0; e < 4; ++e) {
      u64 k = ((u64)__float_as_uint(vv[e]) << 32) | (u64)(~(uint32_t)(jb + e));
      int s = it * 4 + e;
      ck[s * TKT + t] = k;
      if (k < mk) { mk = k; ms = s; }
    }
  }
  for (int it = 8; it < 16; ++it) {
    float4 vq = rp[t + TKT * it];
    int jb = 4 * (t + TKT * it);
    float vv[4] = {vq.x, vq.y, vq.z, vq.w};
#pragma unroll
    for (int e = 0; e < 4; ++e) {
      u64 k = ((u64)__float_as_uint(vv[e]) << 32) | (u64)(~(uint32_t)(jb + e));
      if (k > mk) {
        ck[ms * TKT + t] = k;
        mk = ~0ull;
#pragma unroll
        for (int s = 0; s < 32; ++s) { u64 c = ck[s * TKT + t]; if (c < mk) { mk = c; ms = s; } }
      }
    }
  }
  __syncthreads();

  u64 bk = 0; int bs = 0;
#pragma unroll
  for (int s = 0; s < 32; ++s) { u64 c = ck[s * TKT + t]; if (c > bk) { bk = c; bs = s; } }

  for (int it = 0; it < 32; ++it) {
    u64 k = bk;
#pragma unroll
    for (int o = 32; o >= 1; o >>= 1) { u64 ok = __shfl_xor(k, o); if (ok > k) k = ok; }
    if ((t & 63) == 0) wbest[t >> 6] = k;
    __syncthreads();
    u64 gk = wbest[0];
    if (wbest[1] > gk) gk = wbest[1];
    if (wbest[2] > gk) gk = wbest[2];
    if (t == 0) {
      topv[row * 32 + it] = __uint_as_float((uint32_t)(gk >> 32));
      topi[row * 32 + it] = (int)(~(uint32_t)gk);
    }
    if (bk == gk) {
      ck[bs * TKT + t] = 0;
      bk = 0; bs = 0;
#pragma unroll
      for (int s = 0; s < 32; ++s) { u64 c = ck[s * TKT + t]; if (c > bk) { bk = c; bs = s; } }
    }
    __syncthreads();
  }
}

// ---------------- zero-fill + symmetrizing scatter (0.5v + 0.5v == v exactly) ------
__global__ __launch_bounds__(256) void zero_kernel(float4* __restrict__ out) {
  size_t i = (size_t)blockIdx.x * 256 + threadIdx.x;
  out[i] = make_float4(0.f, 0.f, 0.f, 0.f);
}

__global__ __launch_bounds__(256) void scatter_kernel(
    const float* __restrict__ topv, const int* __restrict__ topi, float* __restrict__ out) {
  int g = blockIdx.x * 256 + threadIdx.x;   // NROW*32 threads
  int row = g >> 5;
  float v = 0.5f * topv[g];
  int j = topi[g];
  atomicAdd(out + (size_t)row * NROW + j, v);
  atomicAdd(out + (size_t)j * NROW + row, v);
}

// ---------------- launch ----------------
extern "C" void kernel_launch(void* const* d_in, const int* in_sizes, int n_in,
                              void* d_out, int out_size, void* d_ws, size_t ws_size,
                              hipStream_t stream)
{
  const float* X  = (const float*)d_in[0];
  const float* W1 = (const float*)d_in[1];
  const float* b1 = (const float*)d_in[2];
  const float* W2 = (const float*)d_in[3];
  const float* b2 = (const float*)d_in[4];
  const float* W3 = (const float*)d_in[5];
  const float* b3 = (const float*)d_in[6];
  float* out = (float*)d_out;

  char* ws = (char*)d_ws;
  size_t off = 0;
  auto carve = [&](size_t bytes) {
    char* p = ws + off;
    off += (bytes + 255) & ~(size_t)255;
    return (void*)p;
  };

  float* h1   = (float*)carve(4ull * NROW * HDIM);
  float* h2   = (float*)carve(4ull * NROW * HDIM);
  float* feat = (float*)carve(4ull * NROW * DFEAT);
  float* fn   = (float*)carve(4ull * NROW * DFEAT);
  float* topv = (float*)carve(4ull * NROW * 32);
  int*   topi = (int*)carve(4ull * NROW * 32);

  // BLIS/AOCL-style K-blocking: KC>=512 -> K=512 unsplit, K=1024 -> (512,512).
  gemmf<0><<<dim3(HDIM / 64, NROW / 64), 256, 0, stream>>>(
      X, W1, b1, nullptr, h1, HDIM, DFEAT, 512, 0, 0, 0);
  gemmf<0><<<dim3(HDIM / 64, NROW / 64), 256, 0, stream>>>(
      h1, W2, b2, nullptr, h2, HDIM, HDIM, 512, 512, 0, 0);
  gemmf<1><<<dim3(DFEAT / 64, NROW / 64), 256, 0, stream>>>(
      h2, W3, b3, X, feat, DFEAT, HDIM, 512, 512, 0, 0);

  // norm + fn (numpy classic 8-scalar-acc pairwise base)
  norm_fn_kernel<<<NROW / 4, 256, 0, stream>>>(feat, fn);

  // sim = relu(fn @ fn^T): single unsplit k=0..511 chain per element
  gemmf<2><<<dim3(NROW / 64, NROW / 64), 256, 0, stream>>>(
      fn, fn, nullptr, nullptr, out, NROW, DFEAT, 512, 0, 0, 0);

  // top-32 per row
  topk_kernel<<<NROW, TKT, 0, stream>>>(out, topv, topi);

  // zero + symmetric scatter
  zero_kernel<<<(int)(((size_t)NROW * NROW / 4) / 256), 256, 0, stream>>>((float4*)out);
  scatter_kernel<<<(NROW * 32) / 256, 256, 0, stream>>>(topv, topi, out);
}

// Round 10
// 3445.029 us; speedup vs baseline: 1.5232x; 1.5232x over previous
//
#include <hip/hip_runtime.h>
#include <stdint.h>
#include <math.h>

typedef unsigned long long u64;

#define NROW 12288
#define DFEAT 512
#define HDIM  1024
#define NB    96   // NROW/128

// ==================================================================================
// NUMERICS CONTRACT (validated round 9, absmax 1.95e-3):
//   - every GEMM C element = single-accumulator FMA chain, k ascending, in panels
//     (512) for K=512 and (512,512) for K=1024, panels merged with one f32 add
//     (BLIS/AOCL KC>=512 blocking);
//   - norm = numpy classic pairwise: x*x rounded separately, 128-blocks with 8
//     scalar accumulators, ((r0+r1)+(r2+r3))+((r4+r5)+(r6+r7)), S=(B0+B1)+(B2+B3),
//     correctly-rounded sqrt, +1e-8f, IEEE f32 divide;
//   - top-32 on u64 (valbits<<32 | ~idx) keys; 0.5v+0.5v symmetric scatter.
// This round changes ONLY scheduling/tiling (128x128 tiles, sim symmetry). Chains
// per element are bit-identical to round 9.
// ==================================================================================

// ---------------- MLP GEMM: 128x128 tile, 8x8/thread (2x2 groups of 4x4) ----------
// MODE 0: store relu(v + bias)      (h1, h2)
// MODE 1: store resid + (v + bias)  (feat = X + h)
// NPANEL: 1 -> K=512 single chain; 2 -> K=1024 chains (512,512) merged with one add.
template <int MODE, int NPANEL>
__global__ __launch_bounds__(256, 3) void gemm128(
    const float* __restrict__ A, const float* __restrict__ B,
    const float* __restrict__ bias, const float* __restrict__ resid,
    float* __restrict__ C, int Nn, int K)
{
  __shared__ float As[32][132];   // [k][m], +4 pad
  __shared__ float Bs[32][132];   // [k][n]
  const int t = threadIdx.x;
  const int tn = t & 15, tm = t >> 4;
  const size_t m0 = (size_t)blockIdx.y * 128, n0 = (size_t)blockIdx.x * 128;

  float cur[2][2][4][4] = {};             // [ih][jh][i][j]
  float tot[2][2][4][4];                  // used only when NPANEL==2

  for (int kt = 0; kt < K; kt += 32) {
#pragma unroll
    for (int u = 0; u < 4; ++u) {
      int f = u * 256 + t;
      int r = f >> 3, c = f & 7;
      float4 va = *(const float4*)(A + (m0 + r) * (size_t)K + kt + 4 * c);
      As[4 * c + 0][r] = va.x; As[4 * c + 1][r] = va.y;
      As[4 * c + 2][r] = va.z; As[4 * c + 3][r] = va.w;
      float4 vb = *(const float4*)(B + (n0 + r) * (size_t)K + kt + 4 * c);
      Bs[4 * c + 0][r] = vb.x; Bs[4 * c + 1][r] = vb.y;
      Bs[4 * c + 2][r] = vb.z; Bs[4 * c + 3][r] = vb.w;
    }
    __syncthreads();
#pragma unroll 4
    for (int kk = 0; kk < 32; ++kk) {
      float4 a0 = *(const float4*)&As[kk][4 * tm];
      float4 a1 = *(const float4*)&As[kk][64 + 4 * tm];
      float4 b0 = *(const float4*)&Bs[kk][4 * tn];
      float4 b1 = *(const float4*)&Bs[kk][64 + 4 * tn];
      float av[2][4] = {{a0.x, a0.y, a0.z, a0.w}, {a1.x, a1.y, a1.z, a1.w}};
      float bv[2][4] = {{b0.x, b0.y, b0.z, b0.w}, {b1.x, b1.y, b1.z, b1.w}};
#pragma unroll
      for (int ih = 0; ih < 2; ++ih)
#pragma unroll
        for (int jh = 0; jh < 2; ++jh)
#pragma unroll
          for (int i = 0; i < 4; ++i)
#pragma unroll
            for (int j = 0; j < 4; ++j)
              cur[ih][jh][i][j] = fmaf(av[ih][i], bv[jh][j], cur[ih][jh][i][j]);
    }
    __syncthreads();
    if (NPANEL == 2) {
      int ke = kt + 32;
      if (ke == 512) {          // first panel ends: move, restart chain
#pragma unroll
        for (int ih = 0; ih < 2; ++ih)
#pragma unroll
          for (int jh = 0; jh < 2; ++jh)
#pragma unroll
            for (int i = 0; i < 4; ++i)
#pragma unroll
              for (int j = 0; j < 4; ++j) {
                tot[ih][jh][i][j] = cur[ih][jh][i][j];
                cur[ih][jh][i][j] = 0.f;
              }
      }
    }
  }
  // final value: NPANEL==1 -> cur; NPANEL==2 -> tot + cur (one add, left-assoc)
#pragma unroll
  for (int ih = 0; ih < 2; ++ih)
#pragma unroll
    for (int i = 0; i < 4; ++i) {
      size_t gm = m0 + 64 * ih + 4 * tm + i;
#pragma unroll
      for (int jh = 0; jh < 2; ++jh) {
        size_t gn = n0 + 64 * jh + 4 * tn;
        float rv[4];
#pragma unroll
        for (int j = 0; j < 4; ++j) {
          float v = (NPANEL == 2) ? (tot[ih][jh][i][j] + cur[ih][jh][i][j])
                                  : cur[ih][jh][i][j];
          v = v + bias[gn + j];
          if (MODE == 0) {
            v = v > 0.f ? v : 0.f;
          } else {
            v = resid[gm * (size_t)Nn + gn + j] + v;
          }
          rv[j] = v;
        }
        float4 res = {rv[0], rv[1], rv[2], rv[3]};
        *(float4*)(C + gm * (size_t)Nn + gn) = res;
      }
    }
}

// ---------------- symmetric sim GEMM: upper-tri blocks, write tile + mirror -------
// sim = relu(fn @ fn^T): s_ij bit-equals s_ji (commutative multiply, same chain),
// so compute bi<=bj only. K=512, single panel.
__global__ __launch_bounds__(256, 4) void gemmsym(
    const float* __restrict__ F, float* __restrict__ C)
{
  __shared__ float As[32][132];
  __shared__ float Bs[32][132];
  const int t = threadIdx.x;
  const int tn = t & 15, tm = t >> 4;

  // decode linear block -> (bi, bj), bi<=bj; S(b) = b*NB - b*(b-1)/2
  int lin = blockIdx.x;
  int bi = (int)(NB + 0.5 - sqrt((NB + 0.5) * (NB + 0.5) - 2.0 * (double)lin));
  if (bi < 0) bi = 0;
  if (bi > NB - 1) bi = NB - 1;
  while (bi + 1 <= NB - 1 && (bi + 1) * NB - ((bi + 1) * bi) / 2 <= lin) ++bi;
  while (bi * NB - (bi * (bi - 1)) / 2 > lin) --bi;
  int bj = bi + (lin - (bi * NB - (bi * (bi - 1)) / 2));

  const size_t m0 = (size_t)bi * 128, n0 = (size_t)bj * 128;

  float cur[2][2][4][4] = {};

  for (int kt = 0; kt < DFEAT; kt += 32) {
#pragma unroll
    for (int u = 0; u < 4; ++u) {
      int f = u * 256 + t;
      int r = f >> 3, c = f & 7;
      float4 va = *(const float4*)(F + (m0 + r) * (size_t)DFEAT + kt + 4 * c);
      As[4 * c + 0][r] = va.x; As[4 * c + 1][r] = va.y;
      As[4 * c + 2][r] = va.z; As[4 * c + 3][r] = va.w;
      float4 vb = *(const float4*)(F + (n0 + r) * (size_t)DFEAT + kt + 4 * c);
      Bs[4 * c + 0][r] = vb.x; Bs[4 * c + 1][r] = vb.y;
      Bs[4 * c + 2][r] = vb.z; Bs[4 * c + 3][r] = vb.w;
    }
    __syncthreads();
#pragma unroll 4
    for (int kk = 0; kk < 32; ++kk) {
      float4 a0 = *(const float4*)&As[kk][4 * tm];
      float4 a1 = *(const float4*)&As[kk][64 + 4 * tm];
      float4 b0 = *(const float4*)&Bs[kk][4 * tn];
      float4 b1 = *(const float4*)&Bs[kk][64 + 4 * tn];
      float av[2][4] = {{a0.x, a0.y, a0.z, a0.w}, {a1.x, a1.y, a1.z, a1.w}};
      float bv[2][4] = {{b0.x, b0.y, b0.z, b0.w}, {b1.x, b1.y, b1.z, b1.w}};
#pragma unroll
      for (int ih = 0; ih < 2; ++ih)
#pragma unroll
        for (int jh = 0; jh < 2; ++jh)
#pragma unroll
          for (int i = 0; i < 4; ++i)
#pragma unroll
            for (int j = 0; j < 4; ++j)
              cur[ih][jh][i][j] = fmaf(av[ih][i], bv[jh][j], cur[ih][jh][i][j]);
    }
    __syncthreads();
  }

  // relu in place
#pragma unroll
  for (int ih = 0; ih < 2; ++ih)
#pragma unroll
    for (int jh = 0; jh < 2; ++jh)
#pragma unroll
      for (int i = 0; i < 4; ++i)
#pragma unroll
        for (int j = 0; j < 4; ++j)
          cur[ih][jh][i][j] = cur[ih][jh][i][j] > 0.f ? cur[ih][jh][i][j] : 0.f;

  // normal tile write
#pragma unroll
  for (int ih = 0; ih < 2; ++ih)
#pragma unroll
    for (int i = 0; i < 4; ++i) {
      size_t gm = m0 + 64 * ih + 4 * tm + i;
#pragma unroll
      for (int jh = 0; jh < 2; ++jh) {
        float4 res = {cur[ih][jh][i][0], cur[ih][jh][i][1],
                      cur[ih][jh][i][2], cur[ih][jh][i][3]};
        *(float4*)(C + gm * (size_t)NROW + n0 + 64 * jh + 4 * tn) = res;
      }
    }
  // mirrored tile write (skip on diagonal blocks)
  if (bi != bj) {
#pragma unroll
    for (int jh = 0; jh < 2; ++jh)
#pragma unroll
      for (int j = 0; j < 4; ++j) {
        size_t gn = n0 + 64 * jh + 4 * tn + j;
#pragma unroll
        for (int ih = 0; ih < 2; ++ih) {
          float4 res = {cur[ih][jh][0][j], cur[ih][jh][1][j],
                        cur[ih][jh][2][j], cur[ih][jh][3][j]};
          *(float4*)(C + gn * (size_t)NROW + m0 + 64 * ih + 4 * tm) = res;
        }
      }
  }
}

// ---------------- norm + fn: numpy classic pairwise (UNCHANGED, bit-critical) -----
__global__ __launch_bounds__(256) void norm_fn_kernel(const float* __restrict__ feat,
                                                      float* __restrict__ fn) {
#pragma clang fp contract(off)
  const int row = blockIdx.x * 4 + (threadIdx.x >> 6);
  const int lane = threadIdx.x & 63;
  const float* fr = feat + (size_t)row * DFEAT;
  float r = 0.f;
  if (lane < 32) {
    const float* bp = fr + (lane >> 3) * 128 + (lane & 7);
    float x = bp[0];
    r = x * x;
#pragma unroll
    for (int i = 8; i <= 120; i += 8) {
      float x2 = bp[i];
      float s = x2 * x2;
      r = r + s;
    }
  }
  float v[32];
#pragma unroll
  for (int j = 0; j < 32; ++j) v[j] = __shfl(r, j);
  float Bv[4];
#pragma unroll
  for (int b = 0; b < 4; ++b) {
    const float* p = v + 8 * b;
    Bv[b] = ((p[0] + p[1]) + (p[2] + p[3])) + ((p[4] + p[5]) + (p[6] + p[7]));
  }
  float S = (Bv[0] + Bv[1]) + (Bv[2] + Bv[3]);
  float den = (float)sqrt((double)S) + 1e-8f;
#pragma unroll
  for (int e = 0; e < 8; ++e) {
    int d = e * 64 + lane;
    fn[(size_t)row * DFEAT + d] = fr[d] / den;
  }
}

// ---------------- per-row top-32 (UNCHANGED) ----------------
#define TKT 192
__global__ __launch_bounds__(TKT) void topk_kernel(
    const float* __restrict__ sim, float* __restrict__ topv, int* __restrict__ topi)
{
  __shared__ u64 ck[32 * TKT];
  __shared__ u64 wbest[3];
  const int row = blockIdx.x, t = threadIdx.x;
  const float4* rp = (const float4*)(sim + (size_t)row * NROW);

  u64 mk = ~0ull; int ms = 0;
#pragma unroll
  for (int it = 0; it < 8; ++it) {
    float4 vq = rp[t + TKT * it];
    int jb = 4 * (t + TKT * it);
    float vv[4] = {vq.x, vq.y, vq.z, vq.w};
#pragma unroll
    for (int e = 0; e < 4; ++e) {
      u64 k = ((u64)__float_as_uint(vv[e]) << 32) | (u64)(~(uint32_t)(jb + e));
      int s = it * 4 + e;
      ck[s * TKT + t] = k;
      if (k < mk) { mk = k; ms = s; }
    }
  }
  for (int it = 8; it < 16; ++it) {
    float4 vq = rp[t + TKT * it];
    int jb = 4 * (t + TKT * it);
    float vv[4] = {vq.x, vq.y, vq.z, vq.w};
#pragma unroll
    for (int e = 0; e < 4; ++e) {
      u64 k = ((u64)__float_as_uint(vv[e]) << 32) | (u64)(~(uint32_t)(jb + e));
      if (k > mk) {
        ck[ms * TKT + t] = k;
        mk = ~0ull;
#pragma unroll
        for (int s = 0; s < 32; ++s) { u64 c = ck[s * TKT + t]; if (c < mk) { mk = c; ms = s; } }
      }
    }
  }
  __syncthreads();

  u64 bk = 0; int bs = 0;
#pragma unroll
  for (int s = 0; s < 32; ++s) { u64 c = ck[s * TKT + t]; if (c > bk) { bk = c; bs = s; } }

  for (int it = 0; it < 32; ++it) {
    u64 k = bk;
#pragma unroll
    for (int o = 32; o >= 1; o >>= 1) { u64 ok = __shfl_xor(k, o); if (ok > k) k = ok; }
    if ((t & 63) == 0) wbest[t >> 6] = k;
    __syncthreads();
    u64 gk = wbest[0];
    if (wbest[1] > gk) gk = wbest[1];
    if (wbest[2] > gk) gk = wbest[2];
    if (t == 0) {
      topv[row * 32 + it] = __uint_as_float((uint32_t)(gk >> 32));
      topi[row * 32 + it] = (int)(~(uint32_t)gk);
    }
    if (bk == gk) {
      ck[bs * TKT + t] = 0;
      bk = 0; bs = 0;
#pragma unroll
      for (int s = 0; s < 32; ++s) { u64 c = ck[s * TKT + t]; if (c > bk) { bk = c; bs = s; } }
    }
    __syncthreads();
  }
}

// ---------------- zero + scatter (UNCHANGED) ----------------
__global__ __launch_bounds__(256) void zero_kernel(float4* __restrict__ out) {
  size_t i = (size_t)blockIdx.x * 256 + threadIdx.x;
  out[i] = make_float4(0.f, 0.f, 0.f, 0.f);
}

__global__ __launch_bounds__(256) void scatter_kernel(
    const float* __restrict__ topv, const int* __restrict__ topi, float* __restrict__ out) {
  int g = blockIdx.x * 256 + threadIdx.x;
  int row = g >> 5;
  float v = 0.5f * topv[g];
  int j = topi[g];
  atomicAdd(out + (size_t)row * NROW + j, v);
  atomicAdd(out + (size_t)j * NROW + row, v);
}

// ---------------- launch ----------------
extern "C" void kernel_launch(void* const* d_in, const int* in_sizes, int n_in,
                              void* d_out, int out_size, void* d_ws, size_t ws_size,
                              hipStream_t stream)
{
  const float* X  = (const float*)d_in[0];
  const float* W1 = (const float*)d_in[1];
  const float* b1 = (const float*)d_in[2];
  const float* W2 = (const float*)d_in[3];
  const float* b2 = (const float*)d_in[4];
  const float* W3 = (const float*)d_in[5];
  const float* b3 = (const float*)d_in[6];
  float* out = (float*)d_out;

  char* ws = (char*)d_ws;
  size_t off = 0;
  auto carve = [&](size_t bytes) {
    char* p = ws + off;
    off += (bytes + 255) & ~(size_t)255;
    return (void*)p;
  };

  float* h1   = (float*)carve(4ull * NROW * HDIM);
  float* h2   = (float*)carve(4ull * NROW * HDIM);
  float* feat = (float*)carve(4ull * NROW * DFEAT);
  float* fn   = (float*)carve(4ull * NROW * DFEAT);
  float* topv = (float*)carve(4ull * NROW * 32);
  int*   topi = (int*)carve(4ull * NROW * 32);

  // MLP (chains bit-identical to round 9: K=512 single, K=1024 -> (512,512))
  gemm128<0, 1><<<dim3(HDIM / 128, NROW / 128), 256, 0, stream>>>(
      X, W1, b1, nullptr, h1, HDIM, DFEAT);
  gemm128<0, 2><<<dim3(HDIM / 128, NROW / 128), 256, 0, stream>>>(
      h1, W2, b2, nullptr, h2, HDIM, HDIM);
  gemm128<1, 2><<<dim3(DFEAT / 128, NROW / 128), 256, 0, stream>>>(
      h2, W3, b3, X, feat, DFEAT, HDIM);

  // norm + fn
  norm_fn_kernel<<<NROW / 4, 256, 0, stream>>>(feat, fn);

  // sim = relu(fn @ fn^T), symmetric: 4656 upper-tri blocks
  gemmsym<<<dim3(NB * (NB + 1) / 2), 256, 0, stream>>>(fn, out);

  // top-32 per row
  topk_kernel<<<NROW, TKT, 0, stream>>>(out, topv, topi);

  // zero + symmetric scatter
  zero_kernel<<<(int)(((size_t)NROW * NROW / 4) / 256), 256, 0, stream>>>((float4*)out);
  scatter_kernel<<<(NROW * 32) / 256, 256, 0, stream>>>(topv, topi, out);
}